// Round 9
// baseline (75.671 us; speedup 1.0000x reference)
//
#include <hip/hip_runtime.h>

#define LATENT 128
#define HIDDEN 256
#define OUTD   128
#define TT     100
#define DECH   64
#define NMACRO 5    // RK4 macro-steps of 20 grid intervals (last = 19)

typedef _Float16 f16x8 __attribute__((ext_vector_type(8)));
typedef float    f32x4 __attribute__((ext_vector_type(4)));

#define MFMA16(a,b,c) __builtin_amdgcn_mfma_f32_16x16x32_f16((a),(b),(c),0,0,0)

__device__ __forceinline__ float tanh_fast(float x){
    float e = __expf(2.f*x);
    return 1.f - 2.f*__builtin_amdgcn_rcpf(e + 1.f);
}

__device__ __forceinline__ f16x8 lds_rd8(const _Float16* b, int sB, int row, int colE){
    int off = row*sB + colE*2; off ^= (row&7)<<4;
    return *(const f16x8*)((const char*)b + off);
}
__device__ __forceinline__ void lds_wr1(_Float16* b, int sB, int row, int colE, float v){
    int off = row*sB + colE*2; off ^= (row&7)<<4;
    *(_Float16*)((char*)b + off) = (_Float16)v;
}
__device__ __forceinline__ float lds_rd1(const _Float16* b, int sB, int row, int colE){
    int off = row*sB + colE*2; off ^= (row&7)<<4;
    return (float)*(const _Float16*)((const char*)b + off);
}

// barrier WITHOUT vmcnt drain: stores stay in flight (LDS ordering via lgkmcnt)
__device__ __forceinline__ void bar_nodrain(){
    asm volatile("s_waitcnt lgkmcnt(0)" ::: "memory");
    __builtin_amdgcn_sched_barrier(0);
    __builtin_amdgcn_s_barrier();
    __builtin_amdgcn_sched_barrier(0);
}

// B-frag gather from row-major fp32 W[K][N]: lane holds B[k0+8*(lane>>4)+i][n]
__device__ __forceinline__ f16x8 gbl_bfrag(const float* W, int ldN, int k0, int n){
    f16x8 f;
#pragma unroll
    for(int i=0;i<8;++i) f[i] = (_Float16)W[(size_t)(k0+i)*ldN + n];
    return f;
}

__global__ __launch_bounds__(512, 2) void ode_decoder_kernel(
    const float* __restrict__ z0, const float* __restrict__ times,
    const float* __restrict__ W1, const float* __restrict__ b1,
    const float* __restrict__ W2, const float* __restrict__ b2,
    const float* __restrict__ dW1, const float* __restrict__ db1,
    const float* __restrict__ dW2, const float* __restrict__ db2,
    const float* __restrict__ dW3, const float* __restrict__ db3,
    float* __restrict__ out)
{
    __shared__ _Float16 z_lds[16*LATENT]           __attribute__((aligned(16))); // 4 KB
    __shared__ _Float16 h_lds[16*HIDDEN]           __attribute__((aligned(16))); // 8 KB
    __shared__ _Float16 epz[(NMACRO+1)*16*LATENT]  __attribute__((aligned(16))); // 24 KB
    __shared__ _Float16 epf[(NMACRO+1)*16*LATENT]  __attribute__((aligned(16))); // 24 KB
    __shared__ _Float16 zint[2][64*LATENT]         __attribute__((aligned(16))); // 32 KB
    __shared__ _Float16 h1i [2][64*DECH]           __attribute__((aligned(16))); // 16 KB
    __shared__ _Float16 h2i [2][64*DECH]           __attribute__((aligned(16))); // 16 KB
    __shared__ float    tl[TT];

    const int tid  = threadIdx.x;
    const int wv   = tid >> 6;
    const int lane = tid & 63;
    const int lr   = lane & 15;
    const int lg   = lane >> 4;
    const int row0 = 4*lg;
    const int gRow0 = blockIdx.x * 16;
    const int nsl  = wv & 3;        // decoder n-slice for dG1/dG2
    const int mtb  = 2*(wv >> 2);   // decoder m-tile base for dG1/dG2

    if(tid < TT) tl[tid] = times[tid];

    // ---------- chain weights in VGPRs (R4-verified layout) ----------
    f16x8 w1f[2][4];
#pragma unroll
    for(int t=0;t<2;++t)
#pragma unroll
        for(int q=0;q<4;++q)
            w1f[t][q] = gbl_bfrag(W1, HIDDEN, 32*q+8*lg, 32*wv+16*t+lr);
    f16x8 w2f[8];
#pragma unroll
    for(int q=0;q<8;++q)
        w2f[q] = gbl_bfrag(W2, LATENT, 32*q+8*lg, 16*wv+lr);

    // ---------- decoder weights in VGPRs (R8 n-parallel slices, 8 frags/wave) ----------
    f16x8 dw1f[4], dw2f[2], dw3f[2];
#pragma unroll
    for(int q=0;q<4;++q) dw1f[q] = gbl_bfrag(dW1, DECH, 32*q+8*lg, 16*nsl+lr);
#pragma unroll
    for(int q=0;q<2;++q) dw2f[q] = gbl_bfrag(dW2, DECH, 32*q+8*lg, 16*nsl+lr);
#pragma unroll
    for(int q=0;q<2;++q) dw3f[q] = gbl_bfrag(dW3, OUTD, 32*q+8*lg, 16*wv+lr);

    const float b1v0 = b1[32*wv+lr], b1v1 = b1[32*wv+16+lr];
    const float b2v  = b2[16*wv+lr];
    const float db1v = db1[16*nsl+lr], db2v = db2[16*nsl+lr];
    const float db3v = db3[16*wv+lr];

    // ---------- state: lane owns z[row0+r][16*wv+lr] ----------
    f32x4 z, acc = {0,0,0,0};
#pragma unroll
    for(int r=0;r<4;++r){
        z[r] = z0[(size_t)(gRow0+row0+r)*LATENT + 16*wv + lr];
        lds_wr1(z_lds, LATENT*2, row0+r, 16*wv+lr, z[r]);
    }
    __syncthreads();

    // ---------- chain segment bodies ----------
    auto G1SEG = [&]{
        f16x8 az[4];
#pragma unroll
        for(int q=0;q<4;++q) az[q] = lds_rd8(z_lds, LATENT*2, lr, 32*q+8*lg);
        f32x4 c0 = {b1v0,b1v0,b1v0,b1v0};
        f32x4 c1 = {b1v1,b1v1,b1v1,b1v1};
#pragma unroll
        for(int q=0;q<4;++q){ c0 = MFMA16(az[q], w1f[0][q], c0); c1 = MFMA16(az[q], w1f[1][q], c1); }
#pragma unroll
        for(int r=0;r<4;++r){
            lds_wr1(h_lds, HIDDEN*2, row0+r, 32*wv+lr,    tanh_fast(c0[r]));
            lds_wr1(h_lds, HIDDEN*2, row0+r, 32*wv+16+lr, tanh_fast(c1[r]));
        }
    };
    auto G2SEG = [&]() -> f32x4 {
        f16x8 ah[8];
#pragma unroll
        for(int q=0;q<8;++q) ah[q] = lds_rd8(h_lds, HIDDEN*2, lr, 32*q+8*lg);
        f32x4 ca = {b2v,b2v,b2v,b2v}, cb = {0,0,0,0};
#pragma unroll
        for(int q=0;q<4;++q){ ca = MFMA16(ah[q], w2f[q], ca); cb = MFMA16(ah[4+q], w2f[4+q], cb); }
        return ca + cb;
    };
    auto WRZ = [&](f32x4 zs){
#pragma unroll
        for(int r=0;r<4;++r) lds_wr1(z_lds, LATENT*2, row0+r, 16*wv+lr, zs[r]);
    };
    auto WREP = [&](int p, f32x4 zz, f32x4 ff){
        _Float16* ez = epz + (size_t)p*16*LATENT;
        _Float16* ef = epf + (size_t)p*16*LATENT;
#pragma unroll
        for(int r=0;r<4;++r){
            lds_wr1(ez, LATENT*2, row0+r, 16*wv+lr, zz[r]);
            lds_wr1(ef, LATENT*2, row0+r, 16*wv+lr, ff[r]);
        }
    };

    // ================= PHASE 1: pure RK4 chain, publish endpoints =================
#pragma unroll 1
    for(int j=0;j<NMACRO;++j){
        const int  m0 = 20*j;
        const int  m1 = (m0+20 < TT-1) ? m0+20 : TT-1;
        const float hj = tl[m1]-tl[m0];

        G1SEG();
        __syncthreads();
        {
            f32x4 k1 = G2SEG();
            WREP(j, z, k1);
            acc = z + k1*(hj*(1.f/6.f));
            WRZ(z + k1*(hj*0.5f));
        }
        __syncthreads();
        G1SEG();
        __syncthreads();
        {
            f32x4 k2 = G2SEG();
            acc += k2*(hj*(1.f/3.f));
            WRZ(z + k2*(hj*0.5f));
        }
        __syncthreads();
        G1SEG();
        __syncthreads();
        {
            f32x4 k3 = G2SEG();
            acc += k3*(hj*(1.f/3.f));
            WRZ(z + k3*hj);
        }
        __syncthreads();
        G1SEG();
        __syncthreads();
        {
            f32x4 k4 = G2SEG();
            z = acc + k4*(hj*(1.f/6.f));
            WRZ(z);
        }
        __syncthreads();
    }
    // tail deriv f(z_end) -> endpoint NMACRO
    G1SEG();
    __syncthreads();
    {
        f32x4 kt = G2SEG();
        WREP(NMACRO, z, kt);
    }
    __syncthreads();

    // ================= PHASE 2: pipelined decode of all 100 points =================
    // round r (0..24): pts 4r..4r+3, interval j=r/5
    auto INTERP4p2 = [&](int r){
        const int j = r/5;
        const float t0 = tl[20*j];
        const int  m1 = (j==NMACRO-1) ? TT-1 : 20*j+20;
        const float hp = tl[m1]-t0, rhp = 1.f/hp;
        const _Float16* ez0 = epz + (size_t)j*16*LATENT;
        const _Float16* ef0 = epf + (size_t)j*16*LATENT;
        const _Float16* ez1 = epz + (size_t)(j+1)*16*LATENT;
        const _Float16* ef1 = epf + (size_t)(j+1)*16*LATENT;
        float zAv[4], fAv[4], zBv[4], fBv[4];
#pragma unroll
        for(int rr=0;rr<4;++rr){
            zAv[rr] = lds_rd1(ez0, LATENT*2, row0+rr, 16*wv+lr);
            fAv[rr] = lds_rd1(ef0, LATENT*2, row0+rr, 16*wv+lr);
            zBv[rr] = lds_rd1(ez1, LATENT*2, row0+rr, 16*wv+lr);
            fBv[rr] = lds_rd1(ef1, LATENT*2, row0+rr, 16*wv+lr);
        }
        _Float16* dst = zint[r&1];
#pragma unroll
        for(int i=0;i<4;++i){
            float th = (tl[4*r+i]-t0)*rhp;
            float t2 = th*th, t3 = t2*th;
            float a0 = 2.f*t3-3.f*t2+1.f, a1 = (t3-2.f*t2+th)*hp;
            float a2 = 3.f*t2-2.f*t3,     a3 = (t3-t2)*hp;
#pragma unroll
            for(int rr=0;rr<4;++rr){
                float v = a0*zAv[rr] + a1*fAv[rr] + a2*zBv[rr] + a3*fBv[rr];
                lds_wr1(dst, LATENT*2, 16*i+row0+rr, 16*wv+lr, v);
            }
        }
    };
    auto DG1p2 = [&](int r){
        const _Float16* zsrc = zint[r&1];
        _Float16* h1 = h1i[r&1];
#pragma unroll
        for(int m=0;m<2;++m){ int mt = mtb+m;
            f32x4 c = {db1v,db1v,db1v,db1v};
#pragma unroll
            for(int q=0;q<4;++q) c = MFMA16(lds_rd8(zsrc, LATENT*2, 16*mt+lr, 32*q+8*lg), dw1f[q], c);
#pragma unroll
            for(int rr=0;rr<4;++rr) lds_wr1(h1, DECH*2, 16*mt+row0+rr, 16*nsl+lr, fmaxf(c[rr],0.f));
        }
    };
    auto DG2p2 = [&](int r){
        const _Float16* h1 = h1i[r&1];
        _Float16* h2 = h2i[r&1];
#pragma unroll
        for(int m=0;m<2;++m){ int mt = mtb+m;
            f32x4 c = {db2v,db2v,db2v,db2v};
#pragma unroll
            for(int q=0;q<2;++q) c = MFMA16(lds_rd8(h1, DECH*2, 16*mt+lr, 32*q+8*lg), dw2f[q], c);
#pragma unroll
            for(int rr=0;rr<4;++rr) lds_wr1(h2, DECH*2, 16*mt+row0+rr, 16*nsl+lr, fmaxf(c[rr],0.f));
        }
    };
    auto DG3p2 = [&](int r){
        const _Float16* h2 = h2i[r&1];
#pragma unroll
        for(int mt=0;mt<4;++mt){
            f32x4 c = {db3v,db3v,db3v,db3v};
#pragma unroll
            for(int q=0;q<2;++q) c = MFMA16(lds_rd8(h2, DECH*2, 16*mt+lr, 32*q+8*lg), dw3f[q], c);
#pragma unroll
            for(int rr=0;rr<4;++rr)
                out[(size_t)(gRow0+row0+rr)*TT*OUTD + (size_t)(4*r+mt)*OUTD + 16*wv+lr] = c[rr];
        }
    };

#pragma unroll 1
    for(int s=0;s<28;++s){
        if(s>=3)           DG3p2(s-3);
        if(s>=2 && s<27)   DG2p2(s-2);
        if(s>=1 && s<26)   DG1p2(s-1);
        if(s<25)           INTERP4p2(s);
        bar_nodrain();
    }
}

extern "C" void kernel_launch(void* const* d_in, const int* in_sizes, int n_in,
                              void* d_out, int out_size, void* d_ws, size_t ws_size,
                              hipStream_t stream) {
    ode_decoder_kernel<<<dim3(256), dim3(512), 0, stream>>>(
        (const float*)d_in[0],  (const float*)d_in[1],
        (const float*)d_in[2],  (const float*)d_in[3],
        (const float*)d_in[4],  (const float*)d_in[5],
        (const float*)d_in[6],  (const float*)d_in[7],
        (const float*)d_in[8],  (const float*)d_in[9],
        (const float*)d_in[10], (const float*)d_in[11],
        (float*)d_out);
}

// Round 10
// 73.453 us; speedup vs baseline: 1.0302x; 1.0302x over previous
//
#include <hip/hip_runtime.h>

#define LATENT 128
#define HIDDEN 256
#define OUTD   128
#define TT     100
#define DECH   64
#define NMACRO 7    // RK4 macro-steps of 16 grid intervals (last = 3)

typedef _Float16 f16x8 __attribute__((ext_vector_type(8)));
typedef float    f32x4 __attribute__((ext_vector_type(4)));

#define MFMA16(a,b,c) __builtin_amdgcn_mfma_f32_16x16x32_f16((a),(b),(c),0,0,0)

__device__ __forceinline__ float tanh_fast(float x){
    float e = __expf(2.f*x);
    return 1.f - 2.f*__builtin_amdgcn_rcpf(e + 1.f);
}

// workgroup barrier WITHOUT vmcnt drain: global stores stay in flight across the
// barrier (all cross-wave communication is LDS-only -> lgkmcnt(0) suffices).
__device__ __forceinline__ void bar_nodrain(){
    __builtin_amdgcn_sched_barrier(0);
    asm volatile("s_waitcnt lgkmcnt(0)" ::: "memory");
    __builtin_amdgcn_sched_barrier(0);
    __builtin_amdgcn_s_barrier();
    __builtin_amdgcn_sched_barrier(0);
}

__device__ __forceinline__ f16x8 lds_rd8(const _Float16* b, int sB, int row, int colE){
    int off = row*sB + colE*2; off ^= (row&7)<<4;
    return *(const f16x8*)((const char*)b + off);
}
__device__ __forceinline__ void lds_wr1(_Float16* b, int sB, int row, int colE, float v){
    int off = row*sB + colE*2; off ^= (row&7)<<4;
    *(_Float16*)((char*)b + off) = (_Float16)v;
}

// B-frag gather from row-major fp32 W[K][N]: lane holds B[k0+8*(lane>>4)+i][n]
__device__ __forceinline__ f16x8 gbl_bfrag(const float* W, int ldN, int k0, int n){
    f16x8 f;
#pragma unroll
    for(int i=0;i<8;++i) f[i] = (_Float16)W[(size_t)(k0+i)*ldN + n];
    return f;
}

__global__ __launch_bounds__(512, 2) void ode_decoder_kernel(
    const float* __restrict__ z0, const float* __restrict__ times,
    const float* __restrict__ W1, const float* __restrict__ b1,
    const float* __restrict__ W2, const float* __restrict__ b2,
    const float* __restrict__ dW1, const float* __restrict__ db1,
    const float* __restrict__ dW2, const float* __restrict__ db2,
    const float* __restrict__ dW3, const float* __restrict__ db3,
    float* __restrict__ out)
{
    __shared__ _Float16 z_lds[16*LATENT]  __attribute__((aligned(16))); // 4 KB
    __shared__ _Float16 h_lds[16*HIDDEN]  __attribute__((aligned(16))); // 8 KB
    __shared__ _Float16 zint0[64*LATENT]  __attribute__((aligned(16))); // 16 KB (4 pts x 16 rows)
    __shared__ _Float16 zint1[64*LATENT]  __attribute__((aligned(16))); // 16 KB
    __shared__ _Float16 h1int[64*DECH]    __attribute__((aligned(16))); // 8 KB
    __shared__ _Float16 h2int[64*DECH]    __attribute__((aligned(16))); // 8 KB
    __shared__ float    tl[TT];

    const int tid  = threadIdx.x;
    const int wv   = tid >> 6;
    const int lane = tid & 63;
    const int lr   = lane & 15;
    const int lg   = lane >> 4;
    const int row0 = 4*lg;
    const int gRow0 = blockIdx.x * 16;
    const int nsl  = wv & 3;        // decoder n-slice for dG1/dG2
    const int mtb  = 2*(wv >> 2);   // decoder m-tile base for dG1/dG2

    if(tid < TT) tl[tid] = times[tid];

    // ---------- chain weights in VGPRs (R4-verified layout) ----------
    f16x8 w1f[2][4];
#pragma unroll
    for(int t=0;t<2;++t)
#pragma unroll
        for(int q=0;q<4;++q)
            w1f[t][q] = gbl_bfrag(W1, HIDDEN, 32*q+8*lg, 32*wv+16*t+lr);
    f16x8 w2f[8];
#pragma unroll
    for(int q=0;q<8;++q)
        w2f[q] = gbl_bfrag(W2, LATENT, 32*q+8*lg, 16*wv+lr);

    // ---------- decoder weights in VGPRs (n-parallel slices, 8 frags/wave) ----------
    f16x8 dw1f[4], dw2f[2], dw3f[2];
#pragma unroll
    for(int q=0;q<4;++q) dw1f[q] = gbl_bfrag(dW1, DECH, 32*q+8*lg, 16*nsl+lr);
#pragma unroll
    for(int q=0;q<2;++q) dw2f[q] = gbl_bfrag(dW2, DECH, 32*q+8*lg, 16*nsl+lr);
#pragma unroll
    for(int q=0;q<2;++q) dw3f[q] = gbl_bfrag(dW3, OUTD, 32*q+8*lg, 16*wv+lr);

    const float b1v0 = b1[32*wv+lr], b1v1 = b1[32*wv+16+lr];
    const float b2v  = b2[16*wv+lr];
    const float db1v = db1[16*nsl+lr], db2v = db2[16*nsl+lr];
    const float db3v = db3[16*wv+lr];

    // ---------- state: lane owns z[row0+r][16*wv+lr] ----------
    f32x4 z, acc = {0,0,0,0};
    f32x4 zA = {0,0,0,0}, fA = {0,0,0,0}, fN = {0,0,0,0};
#pragma unroll
    for(int r=0;r<4;++r){
        z[r] = z0[(size_t)(gRow0+row0+r)*LATENT + 16*wv + lr];
        lds_wr1(z_lds, LATENT*2, row0+r, 16*wv+lr, z[r]);
    }
    bar_nodrain();

    // ---------- chain segment bodies ----------
    auto G1SEG = [&]{
        f16x8 az[4];
#pragma unroll
        for(int q=0;q<4;++q) az[q] = lds_rd8(z_lds, LATENT*2, lr, 32*q+8*lg);
        f32x4 c0 = {b1v0,b1v0,b1v0,b1v0};
        f32x4 c1 = {b1v1,b1v1,b1v1,b1v1};
#pragma unroll
        for(int q=0;q<4;++q){ c0 = MFMA16(az[q], w1f[0][q], c0); c1 = MFMA16(az[q], w1f[1][q], c1); }
#pragma unroll
        for(int r=0;r<4;++r){
            lds_wr1(h_lds, HIDDEN*2, row0+r, 32*wv+lr,    tanh_fast(c0[r]));
            lds_wr1(h_lds, HIDDEN*2, row0+r, 32*wv+16+lr, tanh_fast(c1[r]));
        }
    };
    auto G2SEG = [&]() -> f32x4 {
        f16x8 ah[8];
#pragma unroll
        for(int q=0;q<8;++q) ah[q] = lds_rd8(h_lds, HIDDEN*2, lr, 32*q+8*lg);
        f32x4 ca = {b2v,b2v,b2v,b2v}, cb = {0,0,0,0};
#pragma unroll
        for(int q=0;q<4;++q){ ca = MFMA16(ah[q], w2f[q], ca); cb = MFMA16(ah[4+q], w2f[4+q], cb); }
        return ca + cb;
    };
    auto WRZ = [&](f32x4 zs){
#pragma unroll
        for(int r=0;r<4;++r) lds_wr1(z_lds, LATENT*2, row0+r, 16*wv+lr, zs[r]);
    };
    // Hermite dense output: 4 pts basePt.. of interval [t0,t0+hp] -> dst (pt i at rows 16i..)
    // endpoints: (zA,fA) at t0, (z,fN) at t0+hp
    auto INTERP4 = [&](_Float16* dst, int basePt, float t0, float hp, float rhp){
#pragma unroll
        for(int i=0;i<4;++i){
            float th = (tl[basePt+i]-t0)*rhp;
            float t2 = th*th, t3 = t2*th;
            float a0 = 2.f*t3-3.f*t2+1.f, a1 = (t3-2.f*t2+th)*hp;
            float a2 = 3.f*t2-2.f*t3,     a3 = (t3-t2)*hp;
#pragma unroll
            for(int r=0;r<4;++r){
                float v = a0*zA[r] + a1*fA[r] + a2*z[r] + a3*fN[r];
                lds_wr1(dst, LATENT*2, 16*i+row0+r, 16*wv+lr, v);
            }
        }
    };
    auto DG1 = [&](const _Float16* zsrc){   // wave: n-slice nsl, m-tiles mtb,mtb+1
#pragma unroll
        for(int m=0;m<2;++m){ int mt = mtb+m;
            f32x4 c = {db1v,db1v,db1v,db1v};
#pragma unroll
            for(int q=0;q<4;++q) c = MFMA16(lds_rd8(zsrc, LATENT*2, 16*mt+lr, 32*q+8*lg), dw1f[q], c);
#pragma unroll
            for(int r=0;r<4;++r) lds_wr1(h1int, DECH*2, 16*mt+row0+r, 16*nsl+lr, fmaxf(c[r],0.f));
        }
    };
    auto DG2 = [&]{
#pragma unroll
        for(int m=0;m<2;++m){ int mt = mtb+m;
            f32x4 c = {db2v,db2v,db2v,db2v};
#pragma unroll
            for(int q=0;q<2;++q) c = MFMA16(lds_rd8(h1int, DECH*2, 16*mt+lr, 32*q+8*lg), dw2f[q], c);
#pragma unroll
            for(int r=0;r<4;++r) lds_wr1(h2int, DECH*2, 16*mt+row0+r, 16*nsl+lr, fmaxf(c[r],0.f));
        }
    };
    auto DG3 = [&](int basePt){
#pragma unroll
        for(int mt=0;mt<4;++mt){
            f32x4 c = {db3v,db3v,db3v,db3v};
#pragma unroll
            for(int q=0;q<2;++q) c = MFMA16(lds_rd8(h2int, DECH*2, 16*mt+lr, 32*q+8*lg), dw3f[q], c);
#pragma unroll
            for(int r=0;r<4;++r)
                out[(size_t)(gRow0+row0+r)*TT*OUTD + (size_t)(basePt+mt)*OUTD + 16*wv+lr] = c[r];
        }
    };

    // ---------- main: 7 macro RK4 steps ----------
    // During macro j: decode interval j-1 (pts pP..pP+15) rounds A(s0b..s2a), B, C;
    // rounds C/D tails (DG3_C, DG1/DG2/DG3_D) of interval j-2 spill into s0a/s0b/s1a.
#pragma unroll 1
    for(int j=0;j<NMACRO;++j){
        const int  m0 = 16*j;
        const int  m1 = (m0+16 < TT-1) ? m0+16 : TT-1;
        const float hj = tl[m1]-tl[m0];
        const bool dA = (j>=1);
        const bool dD = (j>=2);
        const int  pP = 16*(j-1);
        const int  pQ = 16*(j-2);
        const float t0  = dA ? tl[pP] : 1.f;
        const float hp  = dA ? (tl[m0]-t0) : 1.f;
        const float rhp = 1.f/hp;

        // s0a
        G1SEG(); if(dD){ DG3(pQ+8); DG1(zint1); }          // DG3_C(j-2), DG1_D(j-2)
        bar_nodrain();
        // s0b
        {
            f32x4 k1 = G2SEG();
            fN = k1;
            if(dD) DG2();                                   // DG2_D(j-2)
            if(dA){ INTERP4(zint0, pP, t0, hp, rhp);        // A
                    INTERP4(zint1, pP+4, t0, hp, rhp); }    // B
            acc = z + k1*(hj*(1.f/6.f));
            WRZ(z + k1*(hj*0.5f));
        }
        bar_nodrain();
        // s1a
        G1SEG(); if(dD) DG3(pQ+12);                         // DG3_D(j-2)
        if(dA) DG1(zint0);                                  // DG1_A
        bar_nodrain();
        // s1b
        {
            f32x4 k2 = G2SEG();
            if(dA){ DG2(); INTERP4(zint0, pP+8, t0, hp, rhp); }  // DG2_A, C
            acc += k2*(hj*(1.f/3.f));
            WRZ(z + k2*(hj*0.5f));
        }
        bar_nodrain();
        // s2a
        G1SEG(); if(dA){ DG3(pP); DG1(zint1); }             // DG3_A, DG1_B
        bar_nodrain();
        // s2b
        {
            f32x4 k3 = G2SEG();
            if(dA){ DG2(); INTERP4(zint1, pP+12, t0, hp, rhp); } // DG2_B, D
            zA = z; fA = fN;                                // after last INTERP of this macro
            acc += k3*(hj*(1.f/3.f));
            WRZ(z + k3*hj);
        }
        bar_nodrain();
        // s3a
        G1SEG(); if(dA){ DG3(pP+4); DG1(zint0); }           // DG3_B, DG1_C
        bar_nodrain();
        // s3b
        {
            f32x4 k4 = G2SEG(); if(dA) DG2();               // DG2_C
            z = acc + k4*(hj*(1.f/6.f));
            WRZ(z);
        }
        bar_nodrain();
    }

    // ---------- tail ----------
    // pending: interval 5 spillover (DG3_C, DG1/DG2/DG3_D) + interval 6 (pts 96..99)
    {
        const int pQ = 16*(NMACRO-2);   // 80: interval 5 base
        const int pL = 16*(NMACRO-1);   // 96: interval 6 base
        // T1a
        G1SEG(); DG3(pQ+8); DG1(zint1);
        bar_nodrain();
        // T1b
        {
            f32x4 k1 = G2SEG();
            fN = k1;
            DG2();
            const float t0t = tl[pL], hpt = tl[TT-1]-t0t, rhpt = 1.f/hpt;
            INTERP4(zint0, pL, t0t, hpt, rhpt);
        }
        bar_nodrain();
        // T2a
        DG3(pQ+12); DG1(zint0);
        bar_nodrain();
        // T2b
        DG2();
        bar_nodrain();
        // T3a
        DG3(pL);
    }
}

extern "C" void kernel_launch(void* const* d_in, const int* in_sizes, int n_in,
                              void* d_out, int out_size, void* d_ws, size_t ws_size,
                              hipStream_t stream) {
    ode_decoder_kernel<<<dim3(256), dim3(512), 0, stream>>>(
        (const float*)d_in[0],  (const float*)d_in[1],
        (const float*)d_in[2],  (const float*)d_in[3],
        (const float*)d_in[4],  (const float*)d_in[5],
        (const float*)d_in[6],  (const float*)d_in[7],
        (const float*)d_in[8],  (const float*)d_in[9],
        (const float*)d_in[10], (const float*)d_in[11],
        (float*)d_out);
}

// Round 11
// 59.400 us; speedup vs baseline: 1.2739x; 1.2366x over previous
//
#include <hip/hip_runtime.h>

#define LATENT 128
#define HIDDEN 256
#define OUTD   128
#define TT     100
#define DECH   64
#define NMACRO 5    // RK4 macro-steps of 20 grid intervals (last = 19)

typedef _Float16 f16x8 __attribute__((ext_vector_type(8)));
typedef float    f32x4 __attribute__((ext_vector_type(4)));

#define MFMA16(a,b,c) __builtin_amdgcn_mfma_f32_16x16x32_f16((a),(b),(c),0,0,0)

__device__ __forceinline__ float tanh_fast(float x){
    float e = __expf(2.f*x);
    return 1.f - 2.f*__builtin_amdgcn_rcpf(e + 1.f);
}

// workgroup barrier WITHOUT vmcnt drain (cross-wave comms are LDS-only)
__device__ __forceinline__ void bar_nodrain(){
    __builtin_amdgcn_sched_barrier(0);
    asm volatile("s_waitcnt lgkmcnt(0)" ::: "memory");
    __builtin_amdgcn_sched_barrier(0);
    __builtin_amdgcn_s_barrier();
    __builtin_amdgcn_sched_barrier(0);
}

__device__ __forceinline__ f16x8 lds_rd8(const _Float16* b, int sB, int row, int colE){
    int off = row*sB + colE*2; off ^= (row&7)<<4;
    return *(const f16x8*)((const char*)b + off);
}
__device__ __forceinline__ void lds_wr1(_Float16* b, int sB, int row, int colE, float v){
    int off = row*sB + colE*2; off ^= (row&7)<<4;
    *(_Float16*)((char*)b + off) = (_Float16)v;
}
// packed 2xf16 write (one ds_write_b32); colE must be even
__device__ __forceinline__ void lds_wr2(_Float16* b, int sB, int row, int colE, float lo, float hi){
    int off = row*sB + colE*2; off ^= (row&7)<<4;
    union { _Float16 h[2]; unsigned u; } pk;
    pk.h[0] = (_Float16)lo; pk.h[1] = (_Float16)hi;
    *(unsigned*)((char*)b + off) = pk.u;
}

// B-frag gather from row-major fp32 W[K][N]: lane holds B[k0+8*(lane>>4)+i][n]
__device__ __forceinline__ f16x8 gbl_bfrag(const float* W, int ldN, int k0, int n){
    f16x8 f;
#pragma unroll
    for(int i=0;i<8;++i) f[i] = (_Float16)W[(size_t)(k0+i)*ldN + n];
    return f;
}
// B-frag gather in the PACKED-h k-order: k_eff(i) = 32q + 4*lg + (i>>1) + 16*(i&1)
__device__ __forceinline__ f16x8 gbl_bfrag_pk(const float* W, int ldN, int q, int lg, int n){
    f16x8 f;
#pragma unroll
    for(int i=0;i<8;++i){
        int k = 32*q + 4*lg + (i>>1) + 16*(i&1);
        f[i] = (_Float16)W[(size_t)k*ldN + n];
    }
    return f;
}

__global__ __launch_bounds__(512, 2) void ode_decoder_kernel(
    const float* __restrict__ z0, const float* __restrict__ times,
    const float* __restrict__ W1, const float* __restrict__ b1,
    const float* __restrict__ W2, const float* __restrict__ b2,
    const float* __restrict__ dW1, const float* __restrict__ db1,
    const float* __restrict__ dW2, const float* __restrict__ db2,
    const float* __restrict__ dW3, const float* __restrict__ db3,
    float* __restrict__ out)
{
    __shared__ _Float16 z_lds[16*LATENT]  __attribute__((aligned(16))); // 4 KB
    __shared__ _Float16 h_lds[16*HIDDEN]  __attribute__((aligned(16))); // 8 KB (packed k-order)
    __shared__ _Float16 epz[16*LATENT]    __attribute__((aligned(16))); // 4 KB endpoint z
    __shared__ _Float16 epf[16*LATENT]    __attribute__((aligned(16))); // 4 KB endpoint f
    __shared__ _Float16 h1i[2][64*DECH]   __attribute__((aligned(16))); // 16 KB (parity dbuf)
    __shared__ _Float16 h2i[2][64*DECH]   __attribute__((aligned(16))); // 16 KB
    __shared__ float    tl[TT];

    const int tid  = threadIdx.x;
    const int wv   = tid >> 6;
    const int lane = tid & 63;
    const int lr   = lane & 15;
    const int lg   = lane >> 4;
    const int row0 = 4*lg;
    const int gRow0 = blockIdx.x * 16;
    const int nsl  = wv & 3;        // decoder n-slice (dG1-combine / dG2)
    const int mtb  = 2*(wv >> 2);   // decoder m-tile base for dG2
    const int ph   = wv >> 2;       // point-half for CMB

    if(tid < TT) tl[tid] = times[tid];

    // ---------- chain weights in VGPRs ----------
    f16x8 w1f[2][4];
#pragma unroll
    for(int t=0;t<2;++t)
#pragma unroll
        for(int q=0;q<4;++q)
            w1f[t][q] = gbl_bfrag(W1, HIDDEN, 32*q+8*lg, 32*wv+16*t+lr);
    f16x8 w2f[8];                      // PACKED k-order to match h_lds packing
#pragma unroll
    for(int q=0;q<8;++q)
        w2f[q] = gbl_bfrag_pk(W2, LATENT, q, lg, 16*wv+lr);

    // ---------- decoder weights in VGPRs ----------
    f16x8 dw1f[4], dw2f[2], dw3f[2];
#pragma unroll
    for(int q=0;q<4;++q) dw1f[q] = gbl_bfrag(dW1, DECH, 32*q+8*lg, 16*nsl+lr);
#pragma unroll
    for(int q=0;q<2;++q) dw2f[q] = gbl_bfrag(dW2, DECH, 32*q+8*lg, 16*nsl+lr);
#pragma unroll
    for(int q=0;q<2;++q) dw3f[q] = gbl_bfrag(dW3, OUTD, 32*q+8*lg, 16*wv+lr);

    const float b1v0 = b1[32*wv+lr], b1v1 = b1[32*wv+16+lr];
    const float b2v  = b2[16*wv+lr];
    const float db1v = db1[16*nsl+lr], db2v = db2[16*nsl+lr];
    const float db3v = db3[16*wv+lr];

    // ---------- state ----------
    f32x4 z, acc = {0,0,0,0};
    f32x4 UA = {0,0,0,0}, VA = {0,0,0,0}, UB = {0,0,0,0}, VB = {0,0,0,0};
#pragma unroll
    for(int r=0;r<4;++r){
        z[r] = z0[(size_t)(gRow0+row0+r)*LATENT + 16*wv + lr];
        lds_wr1(z_lds, LATENT*2, row0+r, 16*wv+lr, z[r]);
    }
    bar_nodrain();

    // ---------- chain segment bodies ----------
    auto G1SEG = [&]{
        f16x8 az[4];
#pragma unroll
        for(int q=0;q<4;++q) az[q] = lds_rd8(z_lds, LATENT*2, lr, 32*q+8*lg);
        f32x4 c0 = {b1v0,b1v0,b1v0,b1v0};
        f32x4 c1 = {b1v1,b1v1,b1v1,b1v1};
#pragma unroll
        for(int q=0;q<4;++q){ c0 = MFMA16(az[q], w1f[0][q], c0); c1 = MFMA16(az[q], w1f[1][q], c1); }
#pragma unroll
        for(int r=0;r<4;++r)
            lds_wr2(h_lds, HIDDEN*2, row0+r, 2*(16*wv+lr), tanh_fast(c0[r]), tanh_fast(c1[r]));
    };
    auto G2SEG = [&]() -> f32x4 {
        f16x8 ah[8];
#pragma unroll
        for(int q=0;q<8;++q) ah[q] = lds_rd8(h_lds, HIDDEN*2, lr, 32*q+8*lg);
        f32x4 ca = {b2v,b2v,b2v,b2v}, cb = {0,0,0,0};
#pragma unroll
        for(int q=0;q<4;++q){ ca = MFMA16(ah[q], w2f[q], ca); cb = MFMA16(ah[4+q], w2f[4+q], cb); }
        return ca + cb;
    };
    auto WRZ = [&](f32x4 zs){
#pragma unroll
        for(int r=0;r<4;++r) lds_wr1(z_lds, LATENT*2, row0+r, 16*wv+lr, zs[r]);
    };
    auto WREP = [&](f32x4 zz, f32x4 ff){
#pragma unroll
        for(int r=0;r<4;++r){
            lds_wr1(epz, LATENT*2, row0+r, 16*wv+lr, zz[r]);
            lds_wr1(epf, LATENT*2, row0+r, 16*wv+lr, ff[r]);
        }
    };
    auto UVGEMM = [&]{   // UB = epz@dW1, VB = epf@dW1 (wave's n-slice; halves duplicate)
        f32x4 u = {0,0,0,0}, v = {0,0,0,0};
#pragma unroll
        for(int q=0;q<4;++q){
            u = MFMA16(lds_rd8(epz, LATENT*2, lr, 32*q+8*lg), dw1f[q], u);
            v = MFMA16(lds_rd8(epf, LATENT*2, lr, 32*q+8*lg), dw1f[q], v);
        }
        UB = u; VB = v;
    };
    // Hermite-combined dG1: h1(p) = relu(a0*UA + a1*VA + a2*UB + a3*VB + db1)
    auto CMB = [&](int par, int p0, int jj){
        const float t0 = tl[20*jj];
        const float tB = (jj==NMACRO-1) ? tl[TT-1] : tl[20*jj+20];
        const float hp = tB - t0, rhp = 1.f/hp;
        _Float16* h1 = h1i[par];
#pragma unroll
        for(int i=0;i<2;++i){
            const int pi = 2*ph + i;              // point index within round (0..3)
            const float th = (tl[p0+pi]-t0)*rhp;
            const float t2 = th*th, t3 = t2*th;
            const float a0 = 2.f*t3-3.f*t2+1.f, a1 = (t3-2.f*t2+th)*hp;
            const float a2 = 3.f*t2-2.f*t3,     a3 = (t3-t2)*hp;
#pragma unroll
            for(int r=0;r<4;++r){
                float v = a0*UA[r] + a1*VA[r] + a2*UB[r] + a3*VB[r] + db1v;
                lds_wr1(h1, DECH*2, 16*pi+row0+r, 16*nsl+lr, fmaxf(v,0.f));
            }
        }
    };
    auto DG2 = [&](int par){
        const _Float16* h1 = h1i[par];
        _Float16* h2 = h2i[par];
#pragma unroll
        for(int m=0;m<2;++m){ int mt = mtb+m;
            f32x4 c = {db2v,db2v,db2v,db2v};
#pragma unroll
            for(int q=0;q<2;++q) c = MFMA16(lds_rd8(h1, DECH*2, 16*mt+lr, 32*q+8*lg), dw2f[q], c);
#pragma unroll
            for(int r=0;r<4;++r) lds_wr1(h2, DECH*2, 16*mt+row0+r, 16*nsl+lr, fmaxf(c[r],0.f));
        }
    };
    auto DG3 = [&](int par, int p0){
        const _Float16* h2 = h2i[par];
#pragma unroll
        for(int mt=0;mt<4;++mt){
            f32x4 c = {db3v,db3v,db3v,db3v};
#pragma unroll
            for(int q=0;q<2;++q) c = MFMA16(lds_rd8(h2, DECH*2, 16*mt+lr, 32*q+8*lg), dw3f[q], c);
#pragma unroll
            for(int r=0;r<4;++r)
                out[(size_t)(gRow0+row0+r)*TT*OUTD + (size_t)(p0+mt)*OUTD + 16*wv+lr] = c[r];
        }
    };

    // ---------- main: 5 macro RK4 steps ----------
    // macro j decodes interval j-1 (rounds rid=rb..rb+4, rb=5(j-1), 4 pts each at p0=4*rid);
    // rounds rb-1, rb-2 (interval j-2) spill their DG2/DG3 into s0a/s0b.
#pragma unroll 1
    for(int j=0;j<NMACRO;++j){
        const int  m0 = 20*j;
        const int  m1 = (m0+20 < TT-1) ? m0+20 : TT-1;
        const float hj = tl[m1]-tl[m0];
        const bool dA = (j>=1);
        const bool dD = (j>=2);
        const int  rb = 5*(j-1);

        // s0a
        G1SEG(); if(dD){ DG2((rb-1)&1); DG3((rb-2)&1, 4*(rb-2)); }
        bar_nodrain();
        // s0b
        {
            f32x4 k1 = G2SEG();
            WREP(z, k1);
            if(dD) DG3((rb-1)&1, 4*(rb-1));
            acc = z + k1*(hj*(1.f/6.f));
            WRZ(z + k1*(hj*0.5f));
        }
        bar_nodrain();
        // s1a
        G1SEG(); UVGEMM();
        bar_nodrain();
        // s1b
        {
            f32x4 k2 = G2SEG();
            if(dA) CMB(rb&1, 4*rb, j-1);
            acc += k2*(hj*(1.f/3.f));
            WRZ(z + k2*(hj*0.5f));
        }
        bar_nodrain();
        // s2a
        G1SEG(); if(dA){ CMB((rb+1)&1, 4*(rb+1), j-1); DG2(rb&1); }
        bar_nodrain();
        // s2b
        {
            f32x4 k3 = G2SEG();
            if(dA){ CMB((rb+2)&1, 4*(rb+2), j-1); DG2((rb+1)&1); DG3(rb&1, 4*rb); }
            acc += k3*(hj*(1.f/3.f));
            WRZ(z + k3*hj);
        }
        bar_nodrain();
        // s3a
        G1SEG(); if(dA){ CMB((rb+3)&1, 4*(rb+3), j-1); DG2((rb+2)&1); DG3((rb+1)&1, 4*(rb+1)); }
        bar_nodrain();
        // s3b
        {
            f32x4 k4 = G2SEG();
            if(dA){ CMB((rb+4)&1, 4*(rb+4), j-1); DG2((rb+3)&1); DG3((rb+2)&1, 4*(rb+2)); }
            z = acc + k4*(hj*(1.f/6.f));
            WRZ(z);
        }
        UA = UB; VA = VB;   // interval j's start-endpoint U/V becomes "A" side
        bar_nodrain();
    }

    // ---------- tail: finish interval 3 spill, then decode interval 4 (rid 20..24) ----------
    {
        // T0a: DG2(rid19), DG3(rid18) + chain eval f(z_end)
        G1SEG(); DG2(19&1); DG3(18&1, 72);
        bar_nodrain();
        // T0b
        {
            f32x4 kt = G2SEG();
            WREP(z, kt);
            DG3(19&1, 76);
        }
        bar_nodrain();
        // T1a
        UVGEMM();
        bar_nodrain();
        // T1b
        CMB(20&1, 80, 4);
        bar_nodrain();
        // T2a
        CMB(21&1, 84, 4); DG2(20&1);
        bar_nodrain();
        // T2b
        CMB(22&1, 88, 4); DG2(21&1); DG3(20&1, 80);
        bar_nodrain();
        // T3a
        CMB(23&1, 92, 4); DG2(22&1); DG3(21&1, 84);
        bar_nodrain();
        // T3b
        CMB(24&1, 96, 4); DG2(23&1); DG3(22&1, 88);
        bar_nodrain();
        // T4a
        DG2(24&1); DG3(23&1, 92);
        bar_nodrain();
        // T4b
        DG3(24&1, 96);
    }
}

extern "C" void kernel_launch(void* const* d_in, const int* in_sizes, int n_in,
                              void* d_out, int out_size, void* d_ws, size_t ws_size,
                              hipStream_t stream) {
    ode_decoder_kernel<<<dim3(256), dim3(512), 0, stream>>>(
        (const float*)d_in[0],  (const float*)d_in[1],
        (const float*)d_in[2],  (const float*)d_in[3],
        (const float*)d_in[4],  (const float*)d_in[5],
        (const float*)d_in[6],  (const float*)d_in[7],
        (const float*)d_in[8],  (const float*)d_in[9],
        (const float*)d_in[10], (const float*)d_in[11],
        (float*)d_out);
}